// Round 1
// baseline (174.375 us; speedup 1.0000x reference)
//
#include <hip/hip_runtime.h>
#include <math.h>

#define NQ    12
#define NST   4096      // 2^12 amplitudes
#define NL    4
#define NBATCH 2048
#define DIM   64
#define NCLS  4
#define TPB   256

// Composition of the layer's CNOT ring: CNOT(0,1),CNOT(1,2),...,CNOT(10,11),CNOT(11,0).
// new_state[d] = old_state[perm(d)]. Qubit q lives at bit position (11-q).
// Derived by reverse-composing g(i) = i ^ (bit_c(i) << pos_t); verified on basis states.
__device__ __forceinline__ unsigned cnot_perm(unsigned i) {
    unsigned s = i ^ ((i & 1u) << 11);       // CNOT(11,0): control bit0, target bit11
    #pragma unroll
    for (int pc = 1; pc <= 11; ++pc)         // CNOT(q,q+1) reversed: control bit pc, target pc-1
        s ^= ((s >> pc) & 1u) << (pc - 1);
    return s;
}

__global__ __launch_bounds__(TPB) void vqc_kernel(
    const float* __restrict__ x,    // [NBATCH, DIM]
    const float* __restrict__ Win,  // [NQ, DIM]
    const float* __restrict__ bin,  // [NQ]
    const float* __restrict__ qw,   // [NL, NQ, 2]
    const float* __restrict__ Wout, // [NCLS, NQ]
    const float* __restrict__ bout, // [NCLS]
    float* __restrict__ out)        // [NBATCH, NCLS]
{
    __shared__ float sre[NST];
    __shared__ float sim[NST];
    __shared__ float xs[DIM];
    // fused gate params per (layer, qubit): RY half-angle cos/sin, RZ full-angle cos/sin
    __shared__ float gC[NL*NQ], gS[NL*NQ], gPC[NL*NQ], gPS[NL*NQ];
    __shared__ float zred[4*NQ];
    __shared__ float zfin[NQ];

    const int tid = threadIdx.x;
    const int b   = blockIdx.x;

    // ---- stage inputs / init state ----
    if (tid < DIM) xs[tid] = x[b*DIM + tid];
    #pragma unroll
    for (int k = 0; k < NST/TPB; ++k) {
        sre[tid + k*TPB] = 0.f;
        sim[tid + k*TPB] = 0.f;
    }
    if (tid == 0) sre[0] = 1.f;
    // layers 1..3 shared gates (no dependency on xs)
    if (tid >= 64 && tid < 64 + 3*NQ) {
        int idx = tid - 64;
        int l = 1 + idx / NQ, q = idx % NQ;
        float th = qw[(l*NQ + q)*2 + 0];
        float ph = qw[(l*NQ + q)*2 + 1];
        float cc, ss; sincosf(0.5f*th, &ss, &cc);
        gC[l*NQ+q] = cc; gS[l*NQ+q] = ss;
        float pcv, psv; sincosf(ph, &psv, &pcv);
        gPC[l*NQ+q] = pcv; gPS[l*NQ+q] = psv;
    }
    __syncthreads();

    // ---- per-sample encoding angles, folded into layer-0 RY ----
    if (tid < NQ) {
        float acc = bin[tid];
        #pragma unroll 8
        for (int d = 0; d < DIM; ++d) acc += xs[d] * Win[tid*DIM + d];
        float ang = tanhf(acc) * 3.14159265358979323846f;
        float th  = ang + qw[(0*NQ + tid)*2 + 0];
        float ph  = qw[(0*NQ + tid)*2 + 1];
        float cc, ss; sincosf(0.5f*th, &ss, &cc);
        gC[tid] = cc; gS[tid] = ss;
        float pcv, psv; sincosf(ph, &psv, &pcv);
        gPC[tid] = pcv; gPS[tid] = psv;
    }
    __syncthreads();

    // ---- circuit: 4 layers of (12 fused RY+RZ gates) + CNOT-ring permutation ----
    for (int l = 0; l < NL; ++l) {
        for (int q = 0; q < NQ; ++q) {
            const float c  = gC[l*NQ+q], s  = gS[l*NQ+q];
            const float pc = gPC[l*NQ+q], ps = gPS[l*NQ+q];
            const int pbit = 11 - q;
            const unsigned mask = 1u << pbit;
            const unsigned lowm = mask - 1u;
            #pragma unroll
            for (int k = 0; k < (NST/2)/TPB; ++k) {
                unsigned j  = (unsigned)tid + (unsigned)(k*TPB);
                unsigned i0 = ((j & ~lowm) << 1) | (j & lowm);
                unsigned i1 = i0 | mask;
                float r0 = sre[i0], m0 = sim[i0];
                float r1 = sre[i1], m1 = sim[i1];
                // RY
                float t0r = c*r0 - s*r1, t0i = c*m0 - s*m1;
                float t1r = s*r0 + c*r1, t1i = s*m0 + c*m1;
                // RZ (global phase dropped): amp1 *= e^{i*phi}
                sre[i0] = t0r; sim[i0] = t0i;
                sre[i1] = pc*t1r - ps*t1i;
                sim[i1] = pc*t1i + ps*t1r;
            }
            __syncthreads();
        }
        // CNOT ring as one permutation: read sources to regs, barrier, write dests
        float tr[NST/TPB], ti[NST/TPB];
        #pragma unroll
        for (int k = 0; k < NST/TPB; ++k) {
            unsigned d = (unsigned)tid + (unsigned)(k*TPB);
            unsigned sidx = cnot_perm(d);
            tr[k] = sre[sidx]; ti[k] = sim[sidx];
        }
        __syncthreads();
        #pragma unroll
        for (int k = 0; k < NST/TPB; ++k) {
            unsigned d = (unsigned)tid + (unsigned)(k*TPB);
            sre[d] = tr[k]; sim[d] = ti[k];
        }
        __syncthreads();
    }

    // ---- PauliZ expectations: z_q = sum_i |amp_i|^2 * (1 - 2*bit(i, 11-q)) ----
    float z[NQ];
    #pragma unroll
    for (int q = 0; q < NQ; ++q) z[q] = 0.f;
    #pragma unroll
    for (int k = 0; k < NST/TPB; ++k) {
        unsigned i = (unsigned)tid + (unsigned)(k*TPB);
        float p = sre[i]*sre[i] + sim[i]*sim[i];
        #pragma unroll
        for (int q = 0; q < NQ; ++q)
            z[q] += ((i >> (11 - q)) & 1u) ? -p : p;
    }
    // wave reduce (64 lanes)
    #pragma unroll
    for (int off = 32; off > 0; off >>= 1) {
        #pragma unroll
        for (int q = 0; q < NQ; ++q)
            z[q] += __shfl_down(z[q], off, 64);
    }
    const int lane = tid & 63, wid = tid >> 6;
    if (lane == 0) {
        #pragma unroll
        for (int q = 0; q < NQ; ++q) zred[wid*NQ + q] = z[q];
    }
    __syncthreads();
    if (tid < NQ)
        zfin[tid] = zred[tid] + zred[NQ+tid] + zred[2*NQ+tid] + zred[3*NQ+tid];
    __syncthreads();

    // ---- classifier head ----
    if (tid < NCLS) {
        float acc = bout[tid];
        #pragma unroll
        for (int q = 0; q < NQ; ++q) acc += zfin[q] * Wout[tid*NQ + q];
        out[b*NCLS + tid] = acc;
    }
}

extern "C" void kernel_launch(void* const* d_in, const int* in_sizes, int n_in,
                              void* d_out, int out_size, void* d_ws, size_t ws_size,
                              hipStream_t stream) {
    const float* x    = (const float*)d_in[0];
    const float* Win  = (const float*)d_in[1];
    const float* bin  = (const float*)d_in[2];
    const float* qw   = (const float*)d_in[3];
    const float* Wout = (const float*)d_in[4];
    const float* bout = (const float*)d_in[5];
    float* out = (float*)d_out;
    hipLaunchKernelGGL(vqc_kernel, dim3(NBATCH), dim3(TPB), 0, stream,
                       x, Win, bin, qw, Wout, bout, out);
}

// Round 2
// 125.193 us; speedup vs baseline: 1.3929x; 1.3929x over previous
//
#include <hip/hip_runtime.h>
#include <math.h>

#define NQ    12
#define NST   4096
#define NL    4
#define NBATCH 2048
#define DIM   64
#define NCLS  4
#define TPB   256
#define APT   16      // amps per thread

// CNOT ring composition (verified in round 1): new[d] = old[cnot_perm(d)].
// XOR-linear: cnot_perm(a^b) = cnot_perm(a)^cnot_perm(b), cnot_perm(0)=0.
__device__ __host__ constexpr unsigned cnot_perm(unsigned i) {
    unsigned s = i ^ ((i & 1u) << 11);
    for (int pc = 1; pc <= 11; ++pc)
        s ^= ((s >> pc) & 1u) << (pc - 1);
    return s;
}

// LDS layout swizzle (float2 index): XOR thread bits 4..6 into bits 1..3.
// Keeps bit0 (float4-pair adjacency) and bits 10..11 (wave-group offsets) intact.
__device__ __forceinline__ unsigned swz(unsigned i) {
    return i ^ (((i >> 4) & 7u) << 1);
}

// lane exchange: partner value at lane ^ XB
template<int XB>
__device__ __forceinline__ float lx(float v) {
    if constexpr (XB == 1) {
        int i = __float_as_int(v);
        return __int_as_float(__builtin_amdgcn_update_dpp(i, i, 0xB1, 0xF, 0xF, true)); // quad_perm [1,0,3,2]
    } else if constexpr (XB == 2) {
        int i = __float_as_int(v);
        return __int_as_float(__builtin_amdgcn_update_dpp(i, i, 0x4E, 0xF, 0xF, true)); // quad_perm [2,3,0,1]
    } else if constexpr (XB == 4) {
        return __int_as_float(__builtin_amdgcn_ds_swizzle(__float_as_int(v), 0x101F)); // xor 4
    } else if constexpr (XB == 8) {
        return __int_as_float(__builtin_amdgcn_ds_swizzle(__float_as_int(v), 0x201F)); // xor 8
    } else if constexpr (XB == 16) {
        return __int_as_float(__builtin_amdgcn_ds_swizzle(__float_as_int(v), 0x401F)); // xor 16
    } else {
        return __shfl_xor(v, 32, 64); // xor 32 crosses the 32-lane halves
    }
}

// gate on an intra-thread bit P (0..3): pairs (k, k|1<<P) in registers
template<int P>
__device__ __forceinline__ void intra_gate(float (&re)[APT], float (&im)[APT],
                                           float c, float s, float pc, float ps) {
    #pragma unroll
    for (int k = 0; k < APT; ++k) {
        if (!(k & (1 << P))) {
            const int k1 = k | (1 << P);
            float r0 = re[k],  m0 = im[k];
            float r1 = re[k1], m1 = im[k1];
            re[k]  = c*r0 - s*r1;
            im[k]  = c*m0 - s*m1;
            float tr = s*r0 + c*r1, ti = s*m0 + c*m1;
            re[k1] = pc*tr - ps*ti;
            im[k1] = pc*ti + ps*tr;
        }
    }
}

// gate on a lane bit P (4..9): exchange partner amp, each lane computes its half
template<int P>
__device__ __forceinline__ void lane_gate(float (&re)[APT], float (&im)[APT],
                                          float c, float s, float pc, float ps, int lane) {
    const int bit = (lane >> (P - 4)) & 1;
    #pragma unroll
    for (int k = 0; k < APT; ++k) {
        float orr = lx<(1 << (P - 4))>(re[k]);
        float oi  = lx<(1 << (P - 4))>(im[k]);
        float mr = re[k], mi = im[k];
        // bit==0: a0' = c*a0 - s*a1 ; bit==1: a1' = e^{i phi} (s*a0 + c*a1)
        float tr = s*orr + c*mr, ti = s*oi + c*mi;
        float r1 = pc*tr - ps*ti, i1 = pc*ti + ps*tr;
        float r0 = c*mr - s*orr,  i0 = c*mi - s*oi;
        re[k] = bit ? r1 : r0;
        im[k] = bit ? i1 : i0;
    }
}

__global__ __launch_bounds__(TPB, 4) void vqc_kernel(
    const float* __restrict__ x,
    const float* __restrict__ Win,
    const float* __restrict__ bin,
    const float* __restrict__ qw,
    const float* __restrict__ Wout,
    const float* __restrict__ bout,
    float* __restrict__ out)
{
    __shared__ float2 buf[NST];          // 32 KB exchange buffer
    __shared__ float xs[DIM];
    __shared__ float gC[NL*NQ], gS[NL*NQ], gPC[NL*NQ], gPS[NL*NQ];
    __shared__ float zred[4*NQ];
    __shared__ float zfin[NQ];

    const int tid  = threadIdx.x;
    const int lane = tid & 63;
    const int b    = blockIdx.x;
    const unsigned base = cnot_perm((unsigned)tid << 4);

    // ---- stage inputs, shared-layer params ----
    if (tid < DIM) xs[tid] = x[b*DIM + tid];
    if (tid >= 64 && tid < 64 + 3*NQ) {
        int idx = tid - 64;
        int l = 1 + idx / NQ, q = idx % NQ;
        float th = qw[(l*NQ + q)*2 + 0];
        float ph = qw[(l*NQ + q)*2 + 1];
        float cc, ss; sincosf(0.5f*th, &ss, &cc);
        gC[l*NQ+q] = cc; gS[l*NQ+q] = ss;
        float pcv, psv; sincosf(ph, &psv, &pcv);
        gPC[l*NQ+q] = pcv; gPS[l*NQ+q] = psv;
    }
    __syncthreads();
    if (tid < NQ) {
        float acc = bin[tid];
        #pragma unroll 8
        for (int d = 0; d < DIM; ++d) acc += xs[d] * Win[tid*DIM + d];
        float ang = tanhf(acc) * 3.14159265358979323846f;
        float th  = ang + qw[(0*NQ + tid)*2 + 0];
        float ph  = qw[(0*NQ + tid)*2 + 1];
        float cc, ss; sincosf(0.5f*th, &ss, &cc);
        gC[tid] = cc; gS[tid] = ss;
        float pcv, psv; sincosf(ph, &psv, &pcv);
        gPC[tid] = pcv; gPS[tid] = psv;
    }
    __syncthreads();

    float re[APT], im[APT];

    // ---- layer 0 on |0..0> is a product state: amp[i] = prod_q Mq[bit,0] ----
    // Mq[:,0] = (c, 0) for bit 0 ; (s*pc, s*ps) for bit 1
    {
        float ar = 1.f, ai = 0.f;
        #pragma unroll
        for (int p = 4; p <= 11; ++p) {
            const int q = 11 - p;
            const int bit = (tid >> (p - 4)) & 1;
            float fr = bit ? gS[q]*gPC[q] : gC[q];
            float fi = bit ? gS[q]*gPS[q] : 0.f;
            float nr = ar*fr - ai*fi;
            float ni = ar*fi + ai*fr;
            ar = nr; ai = ni;
        }
        #pragma unroll
        for (int k = 0; k < APT; ++k) {
            float vr = ar, vi = ai;
            #pragma unroll
            for (int p = 0; p < 4; ++p) {
                const int q = 11 - p;
                const int bit = (k >> p) & 1;
                float fr = bit ? gS[q]*gPC[q] : gC[q];
                float fi = bit ? gS[q]*gPS[q] : 0.f;
                float nr = vr*fr - vi*fi;
                float ni = vr*fi + vi*fr;
                vr = nr; vi = ni;
            }
            re[k] = vr; im[k] = vi;
        }
    }

    // ---- layer-0 ring: one LDS permutation pass ----
    {
        float4* wv = (float4*)buf;
        #pragma unroll
        for (int j = 0; j < 8; ++j) {
            unsigned idx = swz((unsigned)tid*APT + 2u*j) >> 1;
            wv[idx] = make_float4(re[2*j], im[2*j], re[2*j+1], im[2*j+1]);
        }
        __syncthreads();
        #pragma unroll
        for (int k = 0; k < APT; ++k) {
            unsigned jj = base ^ cnot_perm((unsigned)k);
            float2 v = buf[swz(jj)];
            re[k] = v.x; im[k] = v.y;
        }
        __syncthreads();
    }

    // ---- layers 1..3 ----
    for (int l = 1; l < NL; ++l) {
        const float* C  = &gC[l*NQ];
        const float* S  = &gS[l*NQ];
        const float* PC = &gPC[l*NQ];
        const float* PS = &gPS[l*NQ];
        // intra bits 0..3 -> qubits 11..8
        intra_gate<0>(re, im, C[11], S[11], PC[11], PS[11]);
        intra_gate<1>(re, im, C[10], S[10], PC[10], PS[10]);
        intra_gate<2>(re, im, C[9],  S[9],  PC[9],  PS[9]);
        intra_gate<3>(re, im, C[8],  S[8],  PC[8],  PS[8]);
        // lane bits 4..9 -> qubits 7..2
        lane_gate<4>(re, im, C[7], S[7], PC[7], PS[7], lane);
        lane_gate<5>(re, im, C[6], S[6], PC[6], PS[6], lane);
        lane_gate<6>(re, im, C[5], S[5], PC[5], PS[5], lane);
        lane_gate<7>(re, im, C[4], S[4], PC[4], PS[4], lane);
        lane_gate<8>(re, im, C[3], S[3], PC[3], PS[3], lane);
        lane_gate<9>(re, im, C[2], S[2], PC[2], PS[2], lane);
        // fused: gates on bit10 (q=1), bit11 (q=0), then CNOT ring, one LDS pass
        const float c1 = C[1], s1 = S[1], pc1 = PC[1], ps1 = PS[1];
        const float c0 = C[0], s0 = S[0], pc0 = PC[0], ps0 = PS[0];
        {
            float4* wv = (float4*)buf;
            #pragma unroll
            for (int j = 0; j < 8; ++j) {
                unsigned idx = swz((unsigned)tid*APT + 2u*j) >> 1;
                wv[idx] = make_float4(re[2*j], im[2*j], re[2*j+1], im[2*j+1]);
            }
            __syncthreads();
            #pragma unroll
            for (int k = 0; k < APT; ++k) {
                unsigned jj = base ^ cnot_perm((unsigned)k);
                unsigned jb = swz(jj & 0x3FFu);
                const int j10 = (jj >> 10) & 1, j11 = (jj >> 11) & 1;
                float2 p00 = buf[jb];
                float2 p01 = buf[jb | 0x400u];
                float2 p10 = buf[jb | 0x800u];
                float2 p11 = buf[jb | 0xC00u];
                // M10 row j10
                float m0r = j10 ? s1*pc1 : c1,  m0i = j10 ? s1*ps1 : 0.f;
                float m1r = j10 ? c1*pc1 : -s1, m1i = j10 ? c1*ps1 : 0.f;
                float u0r = m0r*p00.x - m0i*p00.y + m1r*p01.x - m1i*p01.y;
                float u0i = m0r*p00.y + m0i*p00.x + m1r*p01.y + m1i*p01.x;
                float u1r = m0r*p10.x - m0i*p10.y + m1r*p11.x - m1i*p11.y;
                float u1i = m0r*p10.y + m0i*p10.x + m1r*p11.y + m1i*p11.x;
                // M11 row j11
                float n0r = j11 ? s0*pc0 : c0,  n0i = j11 ? s0*ps0 : 0.f;
                float n1r = j11 ? c0*pc0 : -s0, n1i = j11 ? c0*ps0 : 0.f;
                re[k] = n0r*u0r - n0i*u0i + n1r*u1r - n1i*u1i;
                im[k] = n0r*u0i + n0i*u0r + n1r*u1i + n1i*u1r;
            }
            __syncthreads();
        }
    }

    // ---- measurement: z_q = sum |amp|^2 * (1-2*bit(i, 11-q)), i = tid*16+k ----
    float psum = 0.f, zk0 = 0.f, zk1 = 0.f, zk2 = 0.f, zk3 = 0.f;
    #pragma unroll
    for (int k = 0; k < APT; ++k) {
        float p = re[k]*re[k] + im[k]*im[k];
        psum += p;
        zk0 += (k & 1) ? -p : p;
        zk1 += (k & 2) ? -p : p;
        zk2 += (k & 4) ? -p : p;
        zk3 += (k & 8) ? -p : p;
    }
    float z[NQ];
    #pragma unroll
    for (int q = 0; q < NQ; ++q) {
        const int pbit = 11 - q;
        if (pbit < 4) {
            z[q] = (pbit == 0) ? zk0 : (pbit == 1) ? zk1 : (pbit == 2) ? zk2 : zk3;
        } else {
            z[q] = ((tid >> (pbit - 4)) & 1) ? -psum : psum;
        }
    }
    #pragma unroll
    for (int off = 32; off > 0; off >>= 1) {
        #pragma unroll
        for (int q = 0; q < NQ; ++q)
            z[q] += __shfl_down(z[q], off, 64);
    }
    const int wid = tid >> 6;
    if (lane == 0) {
        #pragma unroll
        for (int q = 0; q < NQ; ++q) zred[wid*NQ + q] = z[q];
    }
    __syncthreads();
    if (tid < NQ)
        zfin[tid] = zred[tid] + zred[NQ+tid] + zred[2*NQ+tid] + zred[3*NQ+tid];
    __syncthreads();

    if (tid < NCLS) {
        float acc = bout[tid];
        #pragma unroll
        for (int q = 0; q < NQ; ++q) acc += zfin[q] * Wout[tid*NQ + q];
        out[b*NCLS + tid] = acc;
    }
}

extern "C" void kernel_launch(void* const* d_in, const int* in_sizes, int n_in,
                              void* d_out, int out_size, void* d_ws, size_t ws_size,
                              hipStream_t stream) {
    const float* x    = (const float*)d_in[0];
    const float* Win  = (const float*)d_in[1];
    const float* bin  = (const float*)d_in[2];
    const float* qw   = (const float*)d_in[3];
    const float* Wout = (const float*)d_in[4];
    const float* bout = (const float*)d_in[5];
    float* out = (float*)d_out;
    hipLaunchKernelGGL(vqc_kernel, dim3(NBATCH), dim3(TPB), 0, stream,
                       x, Win, bin, qw, Wout, bout, out);
}

// Round 3
// 113.492 us; speedup vs baseline: 1.5365x; 1.1031x over previous
//
#include <hip/hip_runtime.h>
#include <math.h>

#define NQ    12
#define NST   4096
#define NL    4
#define NBATCH 2048
#define DIM   64
#define NCLS  4
#define TPB   256
#define APT   16      // amps per thread

// CNOT ring composition (verified round 1): new[d] = old[cnot_perm(d)].
// XOR-linear: cnot_perm(a^b) = cnot_perm(a)^cnot_perm(b), cnot_perm(0)=0.
__device__ __host__ constexpr unsigned cnot_perm(unsigned i) {
    unsigned s = i ^ ((i & 1u) << 11);
    for (int pc = 1; pc <= 11; ++pc)
        s ^= ((s >> pc) & 1u) << (pc - 1);
    return s;
}

// LDS layout swizzle (float2 index): XOR thread bits 4..6 into bits 1..3.
__device__ __forceinline__ unsigned swz(unsigned i) {
    return i ^ (((i >> 4) & 7u) << 1);
}

// lane exchange: partner value at lane ^ XB
template<int XB>
__device__ __forceinline__ float lx(float v) {
    if constexpr (XB == 1) {
        int i = __float_as_int(v);
        return __int_as_float(__builtin_amdgcn_update_dpp(i, i, 0xB1, 0xF, 0xF, true)); // quad_perm [1,0,3,2]
    } else if constexpr (XB == 2) {
        int i = __float_as_int(v);
        return __int_as_float(__builtin_amdgcn_update_dpp(i, i, 0x4E, 0xF, 0xF, true)); // quad_perm [2,3,0,1]
    } else if constexpr (XB == 4) {
        return __int_as_float(__builtin_amdgcn_ds_swizzle(__float_as_int(v), 0x101F)); // xor 4
    } else if constexpr (XB == 8) {
        return __int_as_float(__builtin_amdgcn_ds_swizzle(__float_as_int(v), 0x201F)); // xor 8
    } else if constexpr (XB == 16) {
        return __int_as_float(__builtin_amdgcn_ds_swizzle(__float_as_int(v), 0x401F)); // xor 16
    } else {
        return __shfl_xor(v, 32, 64); // xor 32 crosses the 32-lane halves
    }
}

// gate on an intra-thread bit P (0..3)
template<int P>
__device__ __forceinline__ void intra_gate(float (&re)[APT], float (&im)[APT],
                                           float c, float s, float pc, float ps) {
    #pragma unroll
    for (int k = 0; k < APT; ++k) {
        if (!(k & (1 << P))) {
            const int k1 = k | (1 << P);
            float r0 = re[k],  m0 = im[k];
            float r1 = re[k1], m1 = im[k1];
            re[k]  = c*r0 - s*r1;
            im[k]  = c*m0 - s*m1;
            float tr = s*r0 + c*r1, ti = s*m0 + c*m1;
            re[k1] = pc*tr - ps*ti;
            im[k1] = pc*ti + ps*tr;
        }
    }
}

// gate on a lane bit P (4..9)
template<int P>
__device__ __forceinline__ void lane_gate(float (&re)[APT], float (&im)[APT],
                                          float c, float s, float pc, float ps, int lane) {
    const int bit = (lane >> (P - 4)) & 1;
    #pragma unroll
    for (int k = 0; k < APT; ++k) {
        float orr = lx<(1 << (P - 4))>(re[k]);
        float oi  = lx<(1 << (P - 4))>(im[k]);
        float mr = re[k], mi = im[k];
        float tr = s*orr + c*mr, ti = s*oi + c*mi;
        float r1 = pc*tr - ps*ti, i1 = pc*ti + ps*tr;
        float r0 = c*mr - s*orr,  i0 = c*mi - s*oi;
        re[k] = bit ? r1 : r0;
        im[k] = bit ? i1 : i0;
    }
}

// launch_bounds(256,2): round-2's (256,4) capped VGPRs at 64 -> ~283 MB/dispatch
// scratch spill (FETCH 100MB + WRITE 176MB). (256,2) allows the ~100-128 VGPRs
// the kernel actually needs; occupancy stays LDS-limited at 4 blocks/CU.
__global__ __launch_bounds__(TPB, 2) void vqc_kernel(
    const float* __restrict__ x,
    const float* __restrict__ Win,
    const float* __restrict__ bin,
    const float* __restrict__ qw,
    const float* __restrict__ Wout,
    const float* __restrict__ bout,
    float* __restrict__ out)
{
    __shared__ float2 buf[NST];          // 32 KB exchange buffer
    __shared__ float xs[DIM];
    __shared__ float gC[NL*NQ], gS[NL*NQ], gPC[NL*NQ], gPS[NL*NQ];
    __shared__ float zred[4*NQ];
    __shared__ float zfin[NQ];

    const int tid  = threadIdx.x;
    const int lane = tid & 63;
    const int b    = blockIdx.x;
    const unsigned base = cnot_perm((unsigned)tid << 4);

    // ---- stage inputs; wave 3 computes layer 1..3 shared-gate params ----
    if (tid < DIM) xs[tid] = x[b*DIM + tid];
    if (tid >= 192 && tid < 192 + 3*NQ) {
        int idx = tid - 192;
        int l = 1 + idx / NQ, q = idx % NQ;
        float th = qw[(l*NQ + q)*2 + 0];
        float ph = qw[(l*NQ + q)*2 + 1];
        float cc, ss; sincosf(0.5f*th, &ss, &cc);
        gC[l*NQ+q] = cc; gS[l*NQ+q] = ss;
        float pcv, psv; sincosf(ph, &psv, &pcv);
        gPC[l*NQ+q] = pcv; gPS[l*NQ+q] = psv;
    }
    __syncthreads();

    // ---- encoding matvec: 16 lanes per qubit, folded into layer-0 RY ----
    if (tid < 192) {
        const int q = tid >> 4, r = tid & 15;
        float acc = xs[r] * Win[q*DIM + r]
                  + xs[r+16] * Win[q*DIM + r + 16]
                  + xs[r+32] * Win[q*DIM + r + 32]
                  + xs[r+48] * Win[q*DIM + r + 48];
        acc += __shfl_xor(acc, 8, 16);
        acc += __shfl_xor(acc, 4, 16);
        acc += __shfl_xor(acc, 2, 16);
        acc += __shfl_xor(acc, 1, 16);
        if (r == 0) {
            acc += bin[q];
            float ang = tanhf(acc) * 3.14159265358979323846f;
            float th  = ang + qw[(0*NQ + q)*2 + 0];
            float ph  = qw[(0*NQ + q)*2 + 1];
            float cc, ss; sincosf(0.5f*th, &ss, &cc);
            gC[q] = cc; gS[q] = ss;
            float pcv, psv; sincosf(ph, &psv, &pcv);
            gPC[q] = pcv; gPS[q] = psv;
        }
    }
    __syncthreads();

    float re[APT], im[APT];

    // ---- layer 0 on |0..0> is a product state: amp[i] = prod_q Mq[bit,0] ----
    {
        float ar = 1.f, ai = 0.f;
        #pragma unroll
        for (int p = 4; p <= 11; ++p) {
            const int q = 11 - p;
            const int bit = (tid >> (p - 4)) & 1;
            float fr = bit ? gS[q]*gPC[q] : gC[q];
            float fi = bit ? gS[q]*gPS[q] : 0.f;
            float nr = ar*fr - ai*fi;
            float ni = ar*fi + ai*fr;
            ar = nr; ai = ni;
        }
        #pragma unroll
        for (int k = 0; k < APT; ++k) {
            float vr = ar, vi = ai;
            #pragma unroll
            for (int p = 0; p < 4; ++p) {
                const int q = 11 - p;
                const int bit = (k >> p) & 1;
                float fr = bit ? gS[q]*gPC[q] : gC[q];
                float fi = bit ? gS[q]*gPS[q] : 0.f;
                float nr = vr*fr - vi*fi;
                float ni = vr*fi + vi*fr;
                vr = nr; vi = ni;
            }
            re[k] = vr; im[k] = vi;
        }
    }

    // ---- layer-0 ring: one LDS permutation pass ----
    {
        float4* wv = (float4*)buf;
        #pragma unroll
        for (int j = 0; j < 8; ++j) {
            unsigned idx = swz((unsigned)tid*APT + 2u*j) >> 1;
            wv[idx] = make_float4(re[2*j], im[2*j], re[2*j+1], im[2*j+1]);
        }
        __syncthreads();
        #pragma unroll
        for (int k = 0; k < APT; ++k) {
            unsigned jj = base ^ cnot_perm((unsigned)k);
            float2 v = buf[swz(jj)];
            re[k] = v.x; im[k] = v.y;
        }
        __syncthreads();
    }

    // ---- layers 1..3 ----
    for (int l = 1; l < NL; ++l) {
        const float* C  = &gC[l*NQ];
        const float* S  = &gS[l*NQ];
        const float* PC = &gPC[l*NQ];
        const float* PS = &gPS[l*NQ];
        intra_gate<0>(re, im, C[11], S[11], PC[11], PS[11]);
        intra_gate<1>(re, im, C[10], S[10], PC[10], PS[10]);
        intra_gate<2>(re, im, C[9],  S[9],  PC[9],  PS[9]);
        intra_gate<3>(re, im, C[8],  S[8],  PC[8],  PS[8]);
        lane_gate<4>(re, im, C[7], S[7], PC[7], PS[7], lane);
        lane_gate<5>(re, im, C[6], S[6], PC[6], PS[6], lane);
        lane_gate<6>(re, im, C[5], S[5], PC[5], PS[5], lane);
        lane_gate<7>(re, im, C[4], S[4], PC[4], PS[4], lane);
        lane_gate<8>(re, im, C[3], S[3], PC[3], PS[3], lane);
        lane_gate<9>(re, im, C[2], S[2], PC[2], PS[2], lane);
        // fused: gates on bit10 (q=1), bit11 (q=0), then CNOT ring, one LDS pass
        const float c1 = C[1], s1 = S[1], pc1 = PC[1], ps1 = PS[1];
        const float c0 = C[0], s0 = S[0], pc0 = PC[0], ps0 = PS[0];
        {
            float4* wv = (float4*)buf;
            #pragma unroll
            for (int j = 0; j < 8; ++j) {
                unsigned idx = swz((unsigned)tid*APT + 2u*j) >> 1;
                wv[idx] = make_float4(re[2*j], im[2*j], re[2*j+1], im[2*j+1]);
            }
            __syncthreads();
            #pragma unroll
            for (int k = 0; k < APT; ++k) {
                unsigned jj = base ^ cnot_perm((unsigned)k);
                unsigned jb = swz(jj & 0x3FFu);
                const int j10 = (jj >> 10) & 1, j11 = (jj >> 11) & 1;
                float2 p00 = buf[jb];
                float2 p01 = buf[jb | 0x400u];
                float2 p10 = buf[jb | 0x800u];
                float2 p11 = buf[jb | 0xC00u];
                float m0r = j10 ? s1*pc1 : c1,  m0i = j10 ? s1*ps1 : 0.f;
                float m1r = j10 ? c1*pc1 : -s1, m1i = j10 ? c1*ps1 : 0.f;
                float u0r = m0r*p00.x - m0i*p00.y + m1r*p01.x - m1i*p01.y;
                float u0i = m0r*p00.y + m0i*p00.x + m1r*p01.y + m1i*p01.x;
                float u1r = m0r*p10.x - m0i*p10.y + m1r*p11.x - m1i*p11.y;
                float u1i = m0r*p10.y + m0i*p10.x + m1r*p11.y + m1i*p11.x;
                float n0r = j11 ? s0*pc0 : c0,  n0i = j11 ? s0*ps0 : 0.f;
                float n1r = j11 ? c0*pc0 : -s0, n1i = j11 ? c0*ps0 : 0.f;
                re[k] = n0r*u0r - n0i*u0i + n1r*u1r - n1i*u1i;
                im[k] = n0r*u0i + n0i*u0r + n1r*u1i + n1i*u1r;
            }
            __syncthreads();
        }
    }

    // ---- measurement ----
    float psum = 0.f, zk0 = 0.f, zk1 = 0.f, zk2 = 0.f, zk3 = 0.f;
    #pragma unroll
    for (int k = 0; k < APT; ++k) {
        float p = re[k]*re[k] + im[k]*im[k];
        psum += p;
        zk0 += (k & 1) ? -p : p;
        zk1 += (k & 2) ? -p : p;
        zk2 += (k & 4) ? -p : p;
        zk3 += (k & 8) ? -p : p;
    }
    float z[NQ];
    #pragma unroll
    for (int q = 0; q < NQ; ++q) {
        const int pbit = 11 - q;
        if (pbit < 4) {
            z[q] = (pbit == 0) ? zk0 : (pbit == 1) ? zk1 : (pbit == 2) ? zk2 : zk3;
        } else {
            z[q] = ((tid >> (pbit - 4)) & 1) ? -psum : psum;
        }
    }
    #pragma unroll
    for (int off = 32; off > 0; off >>= 1) {
        #pragma unroll
        for (int q = 0; q < NQ; ++q)
            z[q] += __shfl_down(z[q], off, 64);
    }
    const int wid = tid >> 6;
    if (lane == 0) {
        #pragma unroll
        for (int q = 0; q < NQ; ++q) zred[wid*NQ + q] = z[q];
    }
    __syncthreads();
    if (tid < NQ)
        zfin[tid] = zred[tid] + zred[NQ+tid] + zred[2*NQ+tid] + zred[3*NQ+tid];
    __syncthreads();

    if (tid < NCLS) {
        float acc = bout[tid];
        #pragma unroll
        for (int q = 0; q < NQ; ++q) acc += zfin[q] * Wout[tid*NQ + q];
        out[b*NCLS + tid] = acc;
    }
}

extern "C" void kernel_launch(void* const* d_in, const int* in_sizes, int n_in,
                              void* d_out, int out_size, void* d_ws, size_t ws_size,
                              hipStream_t stream) {
    const float* x    = (const float*)d_in[0];
    const float* Win  = (const float*)d_in[1];
    const float* bin  = (const float*)d_in[2];
    const float* qw   = (const float*)d_in[3];
    const float* Wout = (const float*)d_in[4];
    const float* bout = (const float*)d_in[5];
    float* out = (float*)d_out;
    hipLaunchKernelGGL(vqc_kernel, dim3(NBATCH), dim3(TPB), 0, stream,
                       x, Win, bin, qw, Wout, bout, out);
}

// Round 4
// 81.488 us; speedup vs baseline: 2.1399x; 1.3927x over previous
//
#include <hip/hip_runtime.h>
#include <math.h>

#define NQ    12
#define NST   4096
#define NL    4
#define NBATCH 2048
#define DIM   64
#define NCLS  4
#define TPB   256
#define APT   16      // amps per thread

// CNOT ring composition (verified round 1): new[d] = old[cnot_perm(d)].
// XOR-linear: cnot_perm(a^b) = cnot_perm(a)^cnot_perm(b), cnot_perm(0)=0.
__device__ __host__ constexpr unsigned cnot_perm(unsigned i) {
    unsigned s = i ^ ((i & 1u) << 11);
    for (int pc = 1; pc <= 11; ++pc)
        s ^= ((s >> pc) & 1u) << (pc - 1);
    return s;
}

// Global LDS swizzle on float2 index: XOR bits 7:4 into 3:0 (bank bits).
// XOR-linear, involution on each 16-f2 block. Makes layout-B reads (k<<8
// stride) and ring-gather reads hit the b64 4-cycle minimum.
__device__ __host__ constexpr unsigned swz(unsigned i) {
    return i ^ ((i >> 4) & 0xFu);
}

// lane exchange: partner value at lane ^ XB (XB in {1,2,4,8} after restructure)
template<int XB>
__device__ __forceinline__ float lx(float v) {
    int i = __float_as_int(v);
    if constexpr (XB == 1) {
        return __int_as_float(__builtin_amdgcn_update_dpp(i, i, 0xB1, 0xF, 0xF, true)); // quad_perm [1,0,3,2]
    } else if constexpr (XB == 2) {
        return __int_as_float(__builtin_amdgcn_update_dpp(i, i, 0x4E, 0xF, 0xF, true)); // quad_perm [2,3,0,1]
    } else if constexpr (XB == 4) {
        return __int_as_float(__builtin_amdgcn_ds_swizzle(i, 0x101F));                  // xor 4
    } else {
        return __int_as_float(__builtin_amdgcn_update_dpp(i, i, 0x128, 0xF, 0xF, true)); // row_ror:8 == lane^8
    }
}

// gate on an intra-thread bit P (0..3) of the register index
template<int P>
__device__ __forceinline__ void intra_gate(float (&re)[APT], float (&im)[APT],
                                           float c, float s, float pc, float ps) {
    #pragma unroll
    for (int k = 0; k < APT; ++k) {
        if (!(k & (1 << P))) {
            const int k1 = k | (1 << P);
            float r0 = re[k],  m0 = im[k];
            float r1 = re[k1], m1 = im[k1];
            re[k]  = c*r0 - s*r1;
            im[k]  = c*m0 - s*m1;
            float tr = s*r0 + c*r1, ti = s*m0 + c*m1;
            re[k1] = pc*tr - ps*ti;
            im[k1] = pc*ti + ps*tr;
        }
    }
}

// gate on lane bit (P-4), hoisted per-lane complex coefficients:
// out = A*mine + B*other;  b=0: A=c, B=-s ;  b=1: A=c*e^{i phi}, B=s*e^{i phi}
template<int P>
__device__ __forceinline__ void lane_gate(float (&re)[APT], float (&im)[APT],
                                          float c, float s, float pc, float ps, int lane) {
    const bool b = (lane >> (P - 4)) & 1;
    const float Ar = b ? c*pc : c;
    const float Ai = b ? c*ps : 0.f;
    const float Br = b ? s*pc : -s;
    const float Bi = b ? s*ps : 0.f;
    #pragma unroll
    for (int k = 0; k < APT; ++k) {
        float orr = lx<(1 << (P - 4))>(re[k]);
        float oi  = lx<(1 << (P - 4))>(im[k]);
        float mr = re[k], mi = im[k];
        re[k] = Ar*mr - Ai*mi + Br*orr - Bi*oi;
        im[k] = Ar*mi + Ai*mr + Br*oi  + Bi*orr;
    }
}

__global__ __launch_bounds__(TPB, 2) void vqc_kernel(
    const float* __restrict__ x,
    const float* __restrict__ Win,
    const float* __restrict__ bin,
    const float* __restrict__ qw,
    const float* __restrict__ Wout,
    const float* __restrict__ bout,
    float* __restrict__ out)
{
    __shared__ float2 buf[NST];          // 32 KB exchange buffer
    __shared__ float xs[DIM];
    __shared__ float gC[NL*NQ], gS[NL*NQ], gPC[NL*NQ], gPS[NL*NQ];
    __shared__ float zred[4*NQ];
    __shared__ float zfin[NQ];

    const int tid  = threadIdx.x;
    const int lane = tid & 63;
    const int wv   = tid >> 6;
    const int b    = blockIdx.x;

    // layout-A write base: f2 addr = (tid<<4) | (k ^ m4)  (= swz((tid<<4)|k))
    const unsigned m4    = (unsigned)tid & 15u;
    const unsigned baseA = ((unsigned)tid << 4) | m4;      // addr = baseA ^ k
    // layout-B base: i = (k<<8)|(l30<<4)|(l54<<2)|wv ; addr = swz(i) = bB + (k<<8)
    const unsigned l30 = (unsigned)lane & 15u, l54 = (unsigned)lane >> 4;
    const unsigned bB  = (l30 << 4) | ((((l54 << 2) | (unsigned)wv)) ^ l30);
    // ring-gather base: addr(k) = swz(P((tid<<4)|k)) = rbase ^ swz(P(k))
    const unsigned rbase = swz(cnot_perm((unsigned)tid << 4));

    // ---- stage inputs; wave 3 computes layer 1..3 shared-gate params ----
    if (tid < DIM) xs[tid] = x[b*DIM + tid];
    if (tid >= 192 && tid < 192 + 3*NQ) {
        int idx = tid - 192;
        int l = 1 + idx / NQ, q = idx % NQ;
        float th = qw[(l*NQ + q)*2 + 0];
        float ph = qw[(l*NQ + q)*2 + 1];
        float cc, ss; sincosf(0.5f*th, &ss, &cc);
        gC[l*NQ+q] = cc; gS[l*NQ+q] = ss;
        float pcv, psv; sincosf(ph, &psv, &pcv);
        gPC[l*NQ+q] = pcv; gPS[l*NQ+q] = psv;
    }
    __syncthreads();

    // ---- encoding matvec: 16 lanes per qubit, folded into layer-0 RY ----
    if (tid < 192) {
        const int q = tid >> 4, r = tid & 15;
        float acc = xs[r] * Win[q*DIM + r]
                  + xs[r+16] * Win[q*DIM + r + 16]
                  + xs[r+32] * Win[q*DIM + r + 32]
                  + xs[r+48] * Win[q*DIM + r + 48];
        acc += __shfl_xor(acc, 8, 16);
        acc += __shfl_xor(acc, 4, 16);
        acc += __shfl_xor(acc, 2, 16);
        acc += __shfl_xor(acc, 1, 16);
        if (r == 0) {
            acc += bin[q];
            float ang = tanhf(acc) * 3.14159265358979323846f;
            float th  = ang + qw[(0*NQ + q)*2 + 0];
            float ph  = qw[(0*NQ + q)*2 + 1];
            float cc, ss; sincosf(0.5f*th, &ss, &cc);
            gC[q] = cc; gS[q] = ss;
            float pcv, psv; sincosf(ph, &psv, &pcv);
            gPC[q] = pcv; gPS[q] = psv;
        }
    }
    __syncthreads();

    float re[APT], im[APT];

    // ---- layer 0 on |0..0> is a product state (layout A) ----
    {
        float ar = 1.f, ai = 0.f;
        #pragma unroll
        for (int p = 4; p <= 11; ++p) {
            const int q = 11 - p;
            const int bit = (tid >> (p - 4)) & 1;
            float fr = bit ? gS[q]*gPC[q] : gC[q];
            float fi = bit ? gS[q]*gPS[q] : 0.f;
            float nr = ar*fr - ai*fi;
            float ni = ar*fi + ai*fr;
            ar = nr; ai = ni;
        }
        #pragma unroll
        for (int k = 0; k < APT; ++k) {
            float vr = ar, vi = ai;
            #pragma unroll
            for (int p = 0; p < 4; ++p) {
                const int q = 11 - p;
                const int bit = (k >> p) & 1;
                float fr = bit ? gS[q]*gPC[q] : gC[q];
                float fi = bit ? gS[q]*gPS[q] : 0.f;
                float nr = vr*fr - vi*fi;
                float ni = vr*fi + vi*fr;
                vr = nr; vi = ni;
            }
            re[k] = vr; im[k] = vi;
        }
    }

    // ---- layer-0 ring: write A, gather ring into A ----
    #pragma unroll
    for (int k = 0; k < APT; ++k)
        buf[baseA ^ (unsigned)k] = make_float2(re[k], im[k]);
    __syncthreads();
    #pragma unroll
    for (int k = 0; k < APT; ++k) {
        float2 v = buf[rbase ^ swz(cnot_perm((unsigned)k))];
        re[k] = v.x; im[k] = v.y;
    }
    __syncthreads();

    // ---- layers 1..3: A-intra(bits0-3) | pass1->B | B-intra(bits8-11) +
    //      lane gates(bits4-7) | pass2 write-back | ring gather -> A ----
    for (int l = 1; l < NL; ++l) {
        const float* C  = &gC[l*NQ];
        const float* S  = &gS[l*NQ];
        const float* PC = &gPC[l*NQ];
        const float* PS = &gPS[l*NQ];
        // layout A: i = tid:k ; bits 0-3 <-> qubits 11-8
        intra_gate<0>(re, im, C[11], S[11], PC[11], PS[11]);
        intra_gate<1>(re, im, C[10], S[10], PC[10], PS[10]);
        intra_gate<2>(re, im, C[9],  S[9],  PC[9],  PS[9]);
        intra_gate<3>(re, im, C[8],  S[8],  PC[8],  PS[8]);
        // pass 1: write A, read B
        #pragma unroll
        for (int k = 0; k < APT; ++k)
            buf[baseA ^ (unsigned)k] = make_float2(re[k], im[k]);
        __syncthreads();
        #pragma unroll
        for (int k = 0; k < APT; ++k) {
            float2 v = buf[bB + ((unsigned)k << 8)];
            re[k] = v.x; im[k] = v.y;
        }
        // layout B: k bits <-> i bits 8-11 <-> qubits 3-0
        intra_gate<0>(re, im, C[3], S[3], PC[3], PS[3]);
        intra_gate<1>(re, im, C[2], S[2], PC[2], PS[2]);
        intra_gate<2>(re, im, C[1], S[1], PC[1], PS[1]);
        intra_gate<3>(re, im, C[0], S[0], PC[0], PS[0]);
        // layout B: lane bits 0-3 <-> i bits 4-7 <-> qubits 7-4
        lane_gate<4>(re, im, C[7], S[7], PC[7], PS[7], lane);
        lane_gate<5>(re, im, C[6], S[6], PC[6], PS[6], lane);
        lane_gate<6>(re, im, C[5], S[5], PC[5], PS[5], lane);
        lane_gate<7>(re, im, C[4], S[4], PC[4], PS[4], lane);
        // pass 2: write back own amps (same addresses we read -> no barrier
        // needed between pass-1 read and this write: per-address same thread)
        #pragma unroll
        for (int k = 0; k < APT; ++k)
            buf[bB + ((unsigned)k << 8)] = make_float2(re[k], im[k]);
        __syncthreads();
        // ring gather into layout A
        #pragma unroll
        for (int k = 0; k < APT; ++k) {
            float2 v = buf[rbase ^ swz(cnot_perm((unsigned)k))];
            re[k] = v.x; im[k] = v.y;
        }
        __syncthreads();
    }

    // ---- measurement (layout A): z_q = sum |amp|^2 * (1-2*bit(i,11-q)) ----
    float psum = 0.f, zk0 = 0.f, zk1 = 0.f, zk2 = 0.f, zk3 = 0.f;
    #pragma unroll
    for (int k = 0; k < APT; ++k) {
        float p = re[k]*re[k] + im[k]*im[k];
        psum += p;
        zk0 += (k & 1) ? -p : p;
        zk1 += (k & 2) ? -p : p;
        zk2 += (k & 4) ? -p : p;
        zk3 += (k & 8) ? -p : p;
    }
    float z[NQ];
    #pragma unroll
    for (int q = 0; q < NQ; ++q) {
        const int pbit = 11 - q;
        if (pbit < 4) {
            z[q] = (pbit == 0) ? zk0 : (pbit == 1) ? zk1 : (pbit == 2) ? zk2 : zk3;
        } else {
            z[q] = ((tid >> (pbit - 4)) & 1) ? -psum : psum;
        }
    }
    #pragma unroll
    for (int off = 32; off > 0; off >>= 1) {
        #pragma unroll
        for (int q = 0; q < NQ; ++q)
            z[q] += __shfl_down(z[q], off, 64);
    }
    const int wid = tid >> 6;
    if (lane == 0) {
        #pragma unroll
        for (int q = 0; q < NQ; ++q) zred[wid*NQ + q] = z[q];
    }
    __syncthreads();
    if (tid < NQ)
        zfin[tid] = zred[tid] + zred[NQ+tid] + zred[2*NQ+tid] + zred[3*NQ+tid];
    __syncthreads();

    if (tid < NCLS) {
        float acc = bout[tid];
        #pragma unroll
        for (int q = 0; q < NQ; ++q) acc += zfin[q] * Wout[tid*NQ + q];
        out[b*NCLS + tid] = acc;
    }
}

extern "C" void kernel_launch(void* const* d_in, const int* in_sizes, int n_in,
                              void* d_out, int out_size, void* d_ws, size_t ws_size,
                              hipStream_t stream) {
    const float* x    = (const float*)d_in[0];
    const float* Win  = (const float*)d_in[1];
    const float* bin  = (const float*)d_in[2];
    const float* qw   = (const float*)d_in[3];
    const float* Wout = (const float*)d_in[4];
    const float* bout = (const float*)d_in[5];
    float* out = (float*)d_out;
    hipLaunchKernelGGL(vqc_kernel, dim3(NBATCH), dim3(TPB), 0, stream,
                       x, Win, bin, qw, Wout, bout, out);
}

// Round 5
// 78.672 us; speedup vs baseline: 2.2165x; 1.0358x over previous
//
#include <hip/hip_runtime.h>
#include <math.h>

#define NQ    12
#define NST   4096
#define NL    4
#define NBATCH 2048
#define DIM   64
#define NCLS  4
#define TPB   512
#define APT   8       // amps per thread

// CNOT ring composition (verified round 1): new[d] = old[cnot_perm(d)].
// XOR-linear. P(e_b) = e_b|e_{b-1} for b>=1 ; P(e_0) = {0,10,11}.
constexpr unsigned cnot_perm(unsigned i) {
    unsigned s = i ^ ((i & 1u) << 11);
    for (int pc = 1; pc <= 11; ++pc)
        s ^= ((s >> pc) & 1u) << (pc - 1);
    return s;
}

// LDS swizzle on f2 index: XOR bits 9:5 into bank bits 4:0. GF(2)-linear,
// bijective. Rank-checked: A-write/B-read/B-write/ring-gather all spread
// 64 lanes over 32 bank-pairs at the b64/b128 minimum.
constexpr unsigned swz(unsigned j) { return j ^ ((j >> 5) & 31u); }

// i_B = (k<<9)|(lane<<3)|wv ; addr = bB ^ BCONST[k], BCONST = swz(k<<9)
__constant__ const unsigned kBC[8] = {0x000,0x210,0x400,0x610,0x800,0xA10,0xC00,0xE10};
// ring gather: addr = rbase ^ swz(P(k)) ; P(k) bits in {0,1,2,10,11} so swz(P(k))=P(k)
__constant__ const unsigned kCK[8] = {0x000,0xC01,0x003,0xC02,0x006,0xC07,0x005,0xC04};

// lane exchange: partner value at lane ^ XB
template<int XB>
__device__ __forceinline__ float lx(float v) {
    int i = __float_as_int(v);
    if constexpr (XB == 1) {
        return __int_as_float(__builtin_amdgcn_update_dpp(i, i, 0xB1, 0xF, 0xF, true));  // quad_perm [1,0,3,2]
    } else if constexpr (XB == 2) {
        return __int_as_float(__builtin_amdgcn_update_dpp(i, i, 0x4E, 0xF, 0xF, true));  // quad_perm [2,3,0,1]
    } else if constexpr (XB == 4) {
        return __int_as_float(__builtin_amdgcn_ds_swizzle(i, 0x101F));                   // xor 4
    } else if constexpr (XB == 8) {
        return __int_as_float(__builtin_amdgcn_update_dpp(i, i, 0x128, 0xF, 0xF, true)); // row_ror:8 == lane^8
    } else if constexpr (XB == 16) {
        return __int_as_float(__builtin_amdgcn_ds_swizzle(i, 0x401F));                   // xor 16
    } else {
        return __shfl_xor(v, 32, 64);
    }
}

// gate on intra-register bit P (0..2). PH=false: RZ dropped (layer 3).
template<int P, bool PH>
__device__ __forceinline__ void intra_g(float (&re)[APT], float (&im)[APT],
                                        float c, float s, float pc, float ps) {
    #pragma unroll
    for (int k = 0; k < APT; ++k) {
        if (!(k & (1 << P))) {
            const int k1 = k | (1 << P);
            float r0 = re[k],  m0 = im[k];
            float r1 = re[k1], m1 = im[k1];
            re[k] = c*r0 - s*r1;
            im[k] = c*m0 - s*m1;
            float tr = s*r0 + c*r1, ti = s*m0 + c*m1;
            if constexpr (PH) {
                re[k1] = pc*tr - ps*ti;
                im[k1] = pc*ti + ps*tr;
            } else {
                re[k1] = tr; im[k1] = ti;
            }
        }
    }
}

// gate on lane bit XB. PH=false: real coefficients only.
template<int XB, bool PH>
__device__ __forceinline__ void lane_g(float (&re)[APT], float (&im)[APT],
                                       float c, float s, float pc, float ps, int lane) {
    const bool b = (lane & XB) != 0;
    if constexpr (PH) {
        const float Ar = b ? c*pc : c;
        const float Ai = b ? c*ps : 0.f;
        const float Br = b ? s*pc : -s;
        const float Bi = b ? s*ps : 0.f;
        #pragma unroll
        for (int k = 0; k < APT; ++k) {
            float orr = lx<XB>(re[k]);
            float oi  = lx<XB>(im[k]);
            float mr = re[k], mi = im[k];
            re[k] = Ar*mr - Ai*mi + Br*orr - Bi*oi;
            im[k] = Ar*mi + Ai*mr + Br*oi  + Bi*orr;
        }
    } else {
        const float Br = b ? s : -s;
        #pragma unroll
        for (int k = 0; k < APT; ++k) {
            float orr = lx<XB>(re[k]);
            float oi  = lx<XB>(im[k]);
            re[k] = c*re[k] + Br*orr;
            im[k] = c*im[k] + Br*oi;
        }
    }
}

__device__ __forceinline__ void a_write(float (&re)[APT], float (&im)[APT],
                                        float2* buf, unsigned baseA, int a0) {
    float4* f4 = (float4*)buf;
    #pragma unroll
    for (int ke = 0; ke < APT; ke += 2) {
        // addr(k)=baseA^k ; even-slot amp has k0==a0 (selects, no runtime reg idx)
        float4 v = a0 ? make_float4(re[ke+1], im[ke+1], re[ke],   im[ke])
                      : make_float4(re[ke],   im[ke],   re[ke+1], im[ke+1]);
        f4[(baseA ^ (unsigned)ke) >> 1] = v;
    }
}

__device__ __forceinline__ void ring_gather(float (&re)[APT], float (&im)[APT],
                                            const float2* buf, unsigned rbase) {
    #pragma unroll
    for (int k = 0; k < APT; ++k) {
        float2 v = buf[rbase ^ kCK[k]];
        re[k] = v.x; im[k] = v.y;
    }
}

template<bool PH>
__device__ __forceinline__ void apply_layer(float (&re)[APT], float (&im)[APT], float2* buf,
    const float* C, const float* S, const float* PCc, const float* PSc,
    unsigned baseA, unsigned bB, unsigned rbase, int lane, int a0) {
    // layout A: i bits 0-2 = k <-> qubits 11,10,9
    intra_g<0,PH>(re, im, C[11], S[11], PCc[11], PSc[11]);
    intra_g<1,PH>(re, im, C[10], S[10], PCc[10], PSc[10]);
    intra_g<2,PH>(re, im, C[9],  S[9],  PCc[9],  PSc[9]);
    a_write(re, im, buf, baseA, a0);
    __syncthreads();
    #pragma unroll
    for (int k = 0; k < APT; ++k) {
        float2 v = buf[bB ^ kBC[k]];
        re[k] = v.x; im[k] = v.y;
    }
    // layout B: i bits 9-11 = k <-> qubits 2,1,0
    intra_g<0,PH>(re, im, C[2], S[2], PCc[2], PSc[2]);
    intra_g<1,PH>(re, im, C[1], S[1], PCc[1], PSc[1]);
    intra_g<2,PH>(re, im, C[0], S[0], PCc[0], PSc[0]);
    // lane bits 0-5 = i bits 3-8 <-> qubits 8..3
    lane_g<1, PH>(re, im, C[8], S[8], PCc[8], PSc[8], lane);
    lane_g<2, PH>(re, im, C[7], S[7], PCc[7], PSc[7], lane);
    lane_g<4, PH>(re, im, C[6], S[6], PCc[6], PSc[6], lane);
    lane_g<8, PH>(re, im, C[5], S[5], PCc[5], PSc[5], lane);
    lane_g<16,PH>(re, im, C[4], S[4], PCc[4], PSc[4], lane);
    lane_g<32,PH>(re, im, C[3], S[3], PCc[3], PSc[3], lane);
    // write back (same addrs we read: per-address same thread, no barrier needed)
    #pragma unroll
    for (int k = 0; k < APT; ++k)
        buf[bB ^ kBC[k]] = make_float2(re[k], im[k]);
    __syncthreads();
    ring_gather(re, im, buf, rbase);
    __syncthreads();
}

__global__ __launch_bounds__(TPB, 6) void vqc_kernel(
    const float* __restrict__ x,
    const float* __restrict__ Win,
    const float* __restrict__ bin,
    const float* __restrict__ qw,
    const float* __restrict__ Wout,
    const float* __restrict__ bout,
    float* __restrict__ out)
{
    __shared__ float2 buf[NST];          // 32 KB exchange buffer
    __shared__ float xs[DIM];
    __shared__ float gC[NL*NQ], gS[NL*NQ], gPC[NL*NQ], gPS[NL*NQ];
    __shared__ float zred[8*10];
    __shared__ float zfin[NQ];

    const int tid  = threadIdx.x;
    const int lane = tid & 63;
    const int wv   = tid >> 6;
    const int b    = blockIdx.x;

    const unsigned baseA = swz((unsigned)tid << 3);                    // addr = baseA ^ k
    const unsigned bB    = swz(((unsigned)lane << 3) | (unsigned)wv);  // addr = bB ^ kBC[k]
    const unsigned rbase = swz(cnot_perm((unsigned)tid << 3));         // addr = rbase ^ kCK[k]
    const int a0 = (int)(baseA & 1u);

    // ---- phase 1: stage x; wave 7 computes layer 1..3 shared-gate params ----
    if (tid < DIM) xs[tid] = x[b*DIM + tid];
    if (tid >= 448 && tid < 448 + 3*NQ) {
        int idx = tid - 448;
        int l = 1 + idx / NQ, q = idx % NQ;
        float th = qw[(l*NQ + q)*2 + 0];
        float cc, ss; sincosf(0.5f*th, &ss, &cc);
        gC[l*NQ+q] = cc; gS[l*NQ+q] = ss;
        if (l < 3) {   // layer-3 RZ dropped (diagonal phase, invisible to |amp|^2)
            float ph = qw[(l*NQ + q)*2 + 1];
            float pcv, psv; sincosf(ph, &psv, &pcv);
            gPC[l*NQ+q] = pcv; gPS[l*NQ+q] = psv;
        }
    }
    __syncthreads();

    // ---- phase 2: encoding matvec, folded into layer-0 RY ----
    if (tid < 192) {
        const int q = tid >> 4, r = tid & 15;
        float acc = xs[r] * Win[q*DIM + r]
                  + xs[r+16] * Win[q*DIM + r + 16]
                  + xs[r+32] * Win[q*DIM + r + 32]
                  + xs[r+48] * Win[q*DIM + r + 48];
        acc += __shfl_xor(acc, 8, 16);
        acc += __shfl_xor(acc, 4, 16);
        acc += __shfl_xor(acc, 2, 16);
        acc += __shfl_xor(acc, 1, 16);
        if (r == 0) {
            acc += bin[q];
            float ang = tanhf(acc) * 3.14159265358979323846f;
            float th  = ang + qw[(0*NQ + q)*2 + 0];
            float ph  = qw[(0*NQ + q)*2 + 1];
            float cc, ss; sincosf(0.5f*th, &ss, &cc);
            gC[q] = cc; gS[q] = ss;
            float pcv, psv; sincosf(ph, &psv, &pcv);
            gPC[q] = pcv; gPS[q] = psv;
        }
    }
    __syncthreads();

    float re[APT], im[APT];

    // ---- layer 0 on |0..0>: product state, hoisted factor tree ----
    {
        // thread factor over i bits 3..11 (qubits 8..0), bit = tid bit (b-3)
        float tr_ = 1.f, ti_ = 0.f;
        #pragma unroll
        for (int p = 3; p <= 11; ++p) {
            const int q = 11 - p;
            const int bit = (tid >> (p - 3)) & 1;
            float fr = bit ? gS[q]*gPC[q] : gC[q];
            float fi = bit ? gS[q]*gPS[q] : 0.f;
            float nr = tr_*fr - ti_*fi;
            float ni = tr_*fi + ti_*fr;
            tr_ = nr; ti_ = ni;
        }
        // k-part tree over bits 0,1,2 (qubits 11,10,9)
        float f0r[2], f0i[2], f1r[2], f1i[2], f2r[2], f2i[2];
        f0r[0] = gC[11]; f0i[0] = 0.f; f0r[1] = gS[11]*gPC[11]; f0i[1] = gS[11]*gPS[11];
        f1r[0] = gC[10]; f1i[0] = 0.f; f1r[1] = gS[10]*gPC[10]; f1i[1] = gS[10]*gPS[10];
        f2r[0] = gC[9];  f2i[0] = 0.f; f2r[1] = gS[9]*gPC[9];   f2i[1] = gS[9]*gPS[9];
        float hr[4], hi[4];
        #pragma unroll
        for (int j = 0; j < 4; ++j) {
            const int b0 = j & 1, b1 = (j >> 1) & 1;
            hr[j] = f0r[b0]*f1r[b1] - f0i[b0]*f1i[b1];
            hi[j] = f0r[b0]*f1i[b1] + f0i[b0]*f1r[b1];
        }
        #pragma unroll
        for (int k = 0; k < APT; ++k) {
            const int j = k & 3, b2 = k >> 2;
            float gr = hr[j]*f2r[b2] - hi[j]*f2i[b2];
            float gi = hr[j]*f2i[b2] + hi[j]*f2r[b2];
            re[k] = tr_*gr - ti_*gi;
            im[k] = tr_*gi + ti_*gr;
        }
    }

    // ---- layer-0 ring ----
    a_write(re, im, buf, baseA, a0);
    __syncthreads();
    ring_gather(re, im, buf, rbase);
    __syncthreads();

    // ---- layers 1..3 (layer 3 without RZ) ----
    apply_layer<true >(re, im, buf, &gC[1*NQ], &gS[1*NQ], &gPC[1*NQ], &gPS[1*NQ], baseA, bB, rbase, lane, a0);
    apply_layer<true >(re, im, buf, &gC[2*NQ], &gS[2*NQ], &gPC[2*NQ], &gPS[2*NQ], baseA, bB, rbase, lane, a0);
    apply_layer<false>(re, im, buf, &gC[3*NQ], &gS[3*NQ], &gPC[3*NQ], &gPS[3*NQ], baseA, bB, rbase, lane, a0);

    // ---- measurement (layout A: i = tid*8+k) ----
    float psum = 0.f, zk0 = 0.f, zk1 = 0.f, zk2 = 0.f;
    #pragma unroll
    for (int k = 0; k < APT; ++k) {
        float p = re[k]*re[k] + im[k]*im[k];
        psum += p;
        zk0 += (k & 1) ? -p : p;     // qubit 11
        zk1 += (k & 2) ? -p : p;     // qubit 10
        zk2 += (k & 4) ? -p : p;     // qubit 9
    }
    // plain wave sums for zk0-2
    #pragma unroll
    for (int off = 1; off < 64; off <<= 1) {
        zk0 += __shfl_xor(zk0, off, 64);
        zk1 += __shfl_xor(zk1, off, 64);
        zk2 += __shfl_xor(zk2, off, 64);
    }
    // WHT butterfly on psum: lane m ends with sum_l psum(l)*(-1)^popc(m&l);
    // lanes {0,1,2,4,8,16,32} hold total + the 6 single-lane-bit signed sums
    float w = psum;
    #pragma unroll
    for (int t = 0; t < 6; ++t) {
        float o = __shfl_xor(w, 1 << t, 64);
        w = ((lane >> t) & 1) ? (o - w) : (w + o);
    }
    if (lane == 0) {
        zred[wv*10 + 0] = zk0;
        zred[wv*10 + 1] = zk1;
        zred[wv*10 + 2] = zk2;
        zred[wv*10 + 3] = w;          // plain psum total
    } else if ((lane & (lane - 1)) == 0) {
        int j = __ffs(lane) - 1;      // lane = 2^j -> qubit 8-j
        zred[wv*10 + 4 + j] = w;
    }
    __syncthreads();
    if (tid < NQ) {
        const int q = tid;
        float acc = 0.f;
        if (q >= 9) {
            const int s_ = 11 - q;
            #pragma unroll
            for (int v2 = 0; v2 < 8; ++v2) acc += zred[v2*10 + s_];
        } else if (q >= 3) {
            const int s_ = 4 + (8 - q);
            #pragma unroll
            for (int v2 = 0; v2 < 8; ++v2) acc += zred[v2*10 + s_];
        } else {
            const int bp = 2 - q;     // qubit 2,1,0 <-> wv bit 0,1,2
            #pragma unroll
            for (int v2 = 0; v2 < 8; ++v2)
                acc += ((v2 >> bp) & 1) ? -zred[v2*10 + 3] : zred[v2*10 + 3];
        }
        zfin[q] = acc;
    }
    __syncthreads();

    // ---- classifier head ----
    if (tid < NCLS) {
        float acc = bout[tid];
        #pragma unroll
        for (int q = 0; q < NQ; ++q) acc += zfin[q] * Wout[tid*NQ + q];
        out[b*NCLS + tid] = acc;
    }
}

extern "C" void kernel_launch(void* const* d_in, const int* in_sizes, int n_in,
                              void* d_out, int out_size, void* d_ws, size_t ws_size,
                              hipStream_t stream) {
    const float* x    = (const float*)d_in[0];
    const float* Win  = (const float*)d_in[1];
    const float* bin  = (const float*)d_in[2];
    const float* qw   = (const float*)d_in[3];
    const float* Wout = (const float*)d_in[4];
    const float* bout = (const float*)d_in[5];
    float* out = (float*)d_out;
    hipLaunchKernelGGL(vqc_kernel, dim3(NBATCH), dim3(TPB), 0, stream,
                       x, Win, bin, qw, Wout, bout, out);
}